// Round 8
// baseline (811.083 us; speedup 1.0000x reference)
//
#include <hip/hip_runtime.h>
#include <hip/hip_bf16.h>
#include <math.h>

typedef __attribute__((ext_vector_type(8))) short s16x8;
typedef __attribute__((ext_vector_type(4))) float f32x4;

static __device__ __forceinline__ float bf2f(unsigned short u){
    unsigned int x = ((unsigned int)u) << 16; float f; __builtin_memcpy(&f,&x,4); return f;
}
static __device__ __forceinline__ unsigned short f2bf(float f){
    unsigned int x; __builtin_memcpy(&x,&f,4);
    unsigned int r = (x + 0x7FFFu + ((x>>16)&1u)) >> 16; return (unsigned short)r;
}

static __device__ __forceinline__ void stage16(const void* g, void* l){
    __builtin_amdgcn_global_load_lds((const __attribute__((address_space(1))) unsigned int*)g,
                                     (__attribute__((address_space(3))) unsigned int*)l, 16, 0, 0);
}

// ---------------- sizes ----------------
// N=64, C=128, T=128, V=25, S=3, K=7
// JN = 3200, NTV = 204800, PADROW = 3350, K-dim = 384*7 = 2688

// ---------------- prep: consts, ffA bf16, wbpart, peb, TPg, ypad halo zero ----------------
__global__ void prep_kernel(const float* __restrict__ out_w, const float* __restrict__ ff_w,
                            const float* __restrict__ v_b,
                            const float* __restrict__ out_b, const float* __restrict__ out_g,
                            const float* __restrict__ out_be, const float* __restrict__ out_m,
                            const float* __restrict__ out_v,
                            const float* __restrict__ ff_b, const float* __restrict__ ff_g,
                            const float* __restrict__ ff_be, const float* __restrict__ ff_m,
                            const float* __restrict__ ff_v,
                            float* __restrict__ consts,
                            unsigned short* __restrict__ ffA, unsigned short* __restrict__ ypad,
                            float* __restrict__ wbpart,
                            float* __restrict__ pebg, float* __restrict__ TPgb)
{
    int stride = gridDim.x*blockDim.x;
    int i0 = blockIdx.x*blockDim.x + threadIdx.x;
    const float KLN = 9.210340371976184f/128.f;   // ln(1e4)/C
    for (int i=i0; i<16384; i+=stride) ffA[i] = f2bf(ff_w[i]);
    for (int i=i0; i<128; i+=stride){
        float inv  = out_g[i]/sqrtf(out_v[i]+1e-5f);
        consts[i]       = inv;
        consts[128+i]   = out_b[i]*inv + out_be[i] - out_m[i]*inv;
        float invf = ff_g[i]/sqrtf(ff_v[i]+1e-5f);
        consts[256+i]   = invf;
        consts[384+i]   = ff_b[i]*invf + ff_be[i] - ff_m[i]*invf;
    }
    // pe table: pebg[v*128 + c]
    for (int i=i0; i<3200; i+=stride){
        int v = i >> 7, c = i & 127;
        float freq = expf(-(float)(c & ~1) * KLN);
        float ang = (float)v * freq;
        pebg[i] = (c & 1) ? cosf(ang) : sinf(ang);
    }
    // TPgb[u*25+v] = T * sum_c pe[c][u]*pe[c][v]
    for (int i=i0; i<625; i+=stride){
        int u = i/25, v = i%25;
        float acc = 0.f;
        for (int c=0; c<128; ++c){
            float freq = expf(-(float)(c & ~1) * KLN);
            float pu = (c & 1) ? cosf((float)u*freq) : sinf((float)u*freq);
            float pv = (c & 1) ? cosf((float)v*freq) : sinf((float)v*freq);
            acc += pu*pv;
        }
        TPgb[i] = 128.f*acc;
    }
    // wbpart[o][s][tc]
    for (int i=i0; i<2688; i+=stride){
        int o = i/21, rem = i%21, s = rem/7, tc = rem%7;
        int kmin = (tc<3) ? (3-tc) : 0;
        int kmax = (tc>3) ? (10-tc) : 7;
        float acc = 0.f;
        for (int c=0; c<128; ++c){
            const float* wp = out_w + (size_t)(o*384 + s*128 + c)*7;
            float vb = v_b[c];
            for (int k=kmin; k<kmax; ++k) acc += wp[k]*vb;
        }
        wbpart[i] = acc;
    }
    // zero the temporal halo pads of Ypad
    for (int i=i0; i<3686400; i+=stride){
        int n2 = i/57600, r2 = i%57600;
        int pp = r2/384, sc = r2%384;
        int ppos = (pp < 75) ? pp : (3200 + pp);
        ypad[(size_t)(n2*3350 + ppos)*384 + sc] = 0;
    }
}

// ---------------- wfold ----------------
__global__ __launch_bounds__(384) void wfold_kernel(const float* __restrict__ out_w,
                                                    const float* __restrict__ v_w,
                                                    unsigned short* __restrict__ Wr){
    __shared__ float owl[384];
    int o = blockIdx.x / 7, k = blockIdx.x % 7;
    int tid = threadIdx.x;
    owl[tid] = out_w[(size_t)(o*384 + tid)*7 + k];
    __syncthreads();
    int s = tid >> 7, ci = tid & 127;
    const float* ow = owl + s*128;
    float acc = 0.f;
    #pragma unroll 8
    for (int c=0; c<128; ++c) acc += ow[c] * v_w[c*128 + ci];
    int kb = (tid>>5)*7 + k, jj = tid & 31;
    Wr[(size_t)o*2688 + kb*32 + jj] = f2bf(acc);
}

// ---------------- x transpose + xbu emit ----------------
__global__ __launch_bounds__(256) void xt_kernel(const float* __restrict__ x,
                                                 unsigned short* __restrict__ xbt,
                                                 unsigned short* __restrict__ xbu){
    __shared__ float tile[64][65];
    int bid = blockIdx.x;
    int jb = bid % 50; int cb = (bid/50) & 1; int n = bid/100;
    int lane = threadIdx.x & 63, wv = threadIdx.x >> 6;
    size_t xbase = (size_t)n*409600;
    int jn = jb*64 + lane;
    int tt = jn/25, uu = jn - tt*25;
    size_t xbu_lb = (size_t)n*524288 + (size_t)tt*4096 + uu;
    #pragma unroll
    for (int r=wv; r<64; r+=4){
        float v = x[xbase + (size_t)(cb*64+r)*3200 + jb*64 + lane];
        tile[r][lane] = v;
        xbu[xbu_lb + (size_t)(cb*64+r)*32] = f2bf(v);
    }
    __syncthreads();
    #pragma unroll
    for (int j=wv; j<64; j+=4)
        xbt[xbase + (size_t)(jb*64+j)*128 + cb*64 + lane] = f2bf(tile[lane][j]);
}

// ---------------- gram via MFMA (unchanged) ----------------
__global__ __launch_bounds__(256) void gram_mfma(const unsigned short* __restrict__ xbt,
                                                 const float* __restrict__ pebg,
                                                 const float* __restrict__ TPgb,
                                                 float* __restrict__ G){
    __shared__ float sxl[25][129];
    __shared__ float pebl[25][129];
    __shared__ float glx[4][32][32];
    int n = blockIdx.x, tid = threadIdx.x;
    const unsigned short* xb = xbt + (size_t)n*409600;

    int c = tid & 127, th = tid >> 7;
    float a[25];
    #pragma unroll
    for (int u=0; u<25; ++u) a[u] = 0.f;
    for (int tt=0; tt<64; ++tt){
        const unsigned short* row = xb + (size_t)(th*64+tt)*3200 + c;
        #pragma unroll
        for (int u=0; u<25; ++u) a[u] += bf2f(row[u*128]);
    }
    float* tmp = &glx[0][0][0];
    if (th){
        #pragma unroll
        for (int u=0; u<25; ++u) tmp[u*128+c] = a[u];
    }
    __syncthreads();
    if (!th){
        #pragma unroll
        for (int u=0; u<25; ++u) sxl[u][c] = a[u] + tmp[u*128+c];
    }
    for (int i=tid; i<3200; i+=256) pebl[i>>7][i&127] = pebg[i];
    __syncthreads();

    int lane = tid & 63, w = tid >> 6;
    int lr = lane & 15, lg = lane >> 4;
    f32x4 acc[2][2];
    #pragma unroll
    for (int i2=0;i2<2;i2++)
        #pragma unroll
        for (int j2=0;j2<2;j2++) acc[i2][j2] = (f32x4){0.f,0.f,0.f,0.f};
    for (int tt=0; tt<32; ++tt){
        int t = tt*4 + w;
        const unsigned short* tb = xb + (size_t)t*3200;
        #pragma unroll
        for (int kc=0; kc<4; ++kc){
            s16x8 f0 = *(const s16x8*)(tb + (size_t)(lr)*128      + kc*32 + lg*8);
            s16x8 f1 = *(const s16x8*)(tb + (size_t)(16+lr)*128   + kc*32 + lg*8);
            acc[0][0] = __builtin_amdgcn_mfma_f32_16x16x32_bf16(f0, f0, acc[0][0], 0,0,0);
            acc[0][1] = __builtin_amdgcn_mfma_f32_16x16x32_bf16(f0, f1, acc[0][1], 0,0,0);
            acc[1][0] = __builtin_amdgcn_mfma_f32_16x16x32_bf16(f1, f0, acc[1][0], 0,0,0);
            acc[1][1] = __builtin_amdgcn_mfma_f32_16x16x32_bf16(f1, f1, acc[1][1], 0,0,0);
        }
    }
    __syncthreads();
    #pragma unroll
    for (int mh=0; mh<2; ++mh)
        #pragma unroll
        for (int nh=0; nh<2; ++nh)
            #pragma unroll
            for (int r=0; r<4; ++r)
                glx[w][mh*16 + lg*4 + r][nh*16 + lr] = acc[mh][nh][r];
    __syncthreads();

    for (int idx=tid; idx<625; idx+=256){
        int u = idx/25, v = idx%25;
        float gx = glx[0][u][v] + glx[1][u][v] + glx[2][u][v] + glx[3][u][v];
        float cr = TPgb[idx];
        #pragma unroll 4
        for (int cc=0; cc<128; ++cc)
            cr += sxl[u][cc]*pebl[v][cc] + sxl[v][cc]*pebl[u][cc];
        G[n*625 + idx] = gx + cr;
    }
}

// ---------------- attention (unchanged) ----------------
__global__ __launch_bounds__(1024) void attn_kernel(const float* __restrict__ G, const float* __restrict__ theta,
                                                    const float* __restrict__ atts, const float* __restrict__ alphas,
                                                    unsigned short* __restrict__ att_pad, float* __restrict__ asum){
    __shared__ float red[1024];
    int tid = threadIdx.x;
    float mx = 0.f;
    for (int idx=tid; idx<40000; idx+=1024){
        int n = idx/625, r = idx%625, u2 = r/25, v2 = r%25;
        const float* Gn = G + n*625;
        float d2v = fmaxf(Gn[u2*26] + Gn[v2*26] - 2.f*Gn[u2*25+v2], 0.f);
        mx = fmaxf(mx, d2v);
    }
    red[tid] = mx; __syncthreads();
    for (int s2=512; s2>0; s2>>=1){ if (tid < s2) red[tid] = fmaxf(red[tid], red[tid+s2]); __syncthreads(); }
    float inv = 1.f/red[0];
    for (int i=tid; i<64*160; i+=1024){
        int n2 = i/160, r2 = i%160;
        att_pad[n2*2560 + 2400 + r2] = 0;
    }
    for (int col=tid; col<4800; col+=1024){
        int n = col/75, r = col%75, s = r/25, vc = r%25;
        const float* Gn = G + n*625;
        float et = expf(theta[s]);
        float al = alphas[s];
        float gvv = Gn[vc*26];
        float z[25];
        #pragma unroll
        for (int u2=0; u2<25; ++u2){
            float d2v = fmaxf(Gn[u2*26] + gvv - 2.f*Gn[u2*25+vc], 0.f);
            z[u2] = expf(-et*d2v*inv);
        }
        float zm = z[0];
        #pragma unroll
        for (int u2=1; u2<25; ++u2) zm = fmaxf(zm, z[u2]);
        float lo = zm - 1.f, hi = zm;
        for (int it=0; it<30; ++it){
            float mid = 0.5f*(lo+hi);
            float f = 0.f;
            #pragma unroll
            for (int u2=0; u2<25; ++u2) f += fmaxf(z[u2]-mid, 0.f);
            if (f >= 1.f) lo = mid; else hi = mid;
        }
        float ssum = 0.f; int kcnt = 0;
        #pragma unroll
        for (int u2=0; u2<25; ++u2){ if (z[u2] > lo){ ssum += z[u2]; kcnt++; } }
        float tau = (ssum - 1.f)/(float)kcnt;
        float as_ = 0.f;
        unsigned short* apr = att_pad + n*2560 + (s*25+vc)*32;
        #pragma unroll
        for (int u2=0; u2<25; ++u2){
            float av = atts[s*625 + u2*25 + vc] + fmaxf(z[u2]-tau, 0.f)*al;
            apr[u2] = f2bf(av);
            as_ += av;
        }
        #pragma unroll
        for (int u2=25; u2<32; ++u2) apr[u2] = 0;
        asum[n*75 + s*25 + vc] = as_;
    }
}

// ---------------- agg via MFMA (unchanged) ----------------
__global__ __launch_bounds__(256,2) void agg_mfma(const unsigned short* __restrict__ att_pad,
                                                  const unsigned short* __restrict__ xbu,
                                                  unsigned short* __restrict__ ypad){
    int bid = blockIdx.x; int n = bid >> 4; int tb = bid & 15;
    int tid = threadIdx.x; int lane = tid & 63; int w = tid >> 6;
    int lr = lane & 15, lg = lane >> 4;
    const unsigned short* ap = att_pad + n*2560;
    s16x8 a[5];
    #pragma unroll
    for (int mf=0; mf<5; ++mf) a[mf] = *(const s16x8*)&ap[(mf*16+lr)*32 + lg*8];
    int rowoff[5][4];
    #pragma unroll
    for (int mf=0; mf<5; ++mf)
        #pragma unroll
        for (int r=0; r<4; ++r){
            int m = mf*16 + lg*4 + r;
            int s = m/25, v = m - s*25;
            rowoff[mf][r] = (m < 75) ? (v*384 + s*128 + lr) : -1;
        }
    #pragma unroll
    for (int ti=0; ti<2; ++ti){
        int t = tb*8 + w*2 + ti;
        const unsigned short* bp = xbu + (size_t)n*524288 + (size_t)t*4096;
        size_t obase = ((size_t)(n*3350 + 75 + t*25))*384;
        #pragma unroll
        for (int h=0; h<2; ++h){
            s16x8 b[4];
            #pragma unroll
            for (int q=0; q<4; ++q) b[q] = *(const s16x8*)&bp[(h*64 + q*16 + lr)*32 + lg*8];
            f32x4 acc[5][4];
            #pragma unroll
            for (int mf=0; mf<5; ++mf)
                #pragma unroll
                for (int q=0; q<4; ++q)
                    acc[mf][q] = (f32x4){0.f,0.f,0.f,0.f};
            #pragma unroll
            for (int mf=0; mf<5; ++mf)
                #pragma unroll
                for (int q=0; q<4; ++q)
                    acc[mf][q] = __builtin_amdgcn_mfma_f32_16x16x32_bf16(a[mf], b[q], acc[mf][q], 0, 0, 0);
            #pragma unroll
            for (int mf=0; mf<5; ++mf)
                #pragma unroll
                for (int q=0; q<4; ++q)
                    #pragma unroll
                    for (int r=0; r<4; ++r)
                        if (rowoff[mf][r] >= 0)
                            ypad[obase + rowoff[mf][r] + h*64 + q*16] = f2bf(acc[mf][q][r]);
        }
    }
}

// ---------------- fused conv+ff GEMM v3b: A from L2 (C++ loads), B-only LDS, BK=64 ----------------
__global__ __launch_bounds__(256,3) void gemm_fused(const unsigned short* __restrict__ Amat,
                                                    const unsigned short* __restrict__ Bsrc,
                                                    const float* __restrict__ xin,
                                                    const float* __restrict__ consts,
                                                    const unsigned short* __restrict__ ffA,
                                                    const float* __restrict__ wbpart,
                                                    const float* __restrict__ asum,
                                                    float* __restrict__ outf)
{
    constexpr int NKB = 42;                      // 42 x BK=64 (pairs of k32 blocks)
    __shared__ unsigned short smem[24576];       // 3 x B-tile(128x64) = 48 KB; reused by epilogue

    const int tid = threadIdx.x;
    const int bid = blockIdx.x;
    const int n   = bid/25;
    const int jn0 = (bid%25)*128;

    const int lane = tid & 63, wv = tid >> 6;
    const int wm = wv >> 1, wn = wv & 1;
    const int lr = lane & 15, lg = lane >> 4;
    const int swz = (lg ^ ((lr>>1)&3)) << 3;

    // B staging geometry: per half j (4096 shorts = 128 rows x 32), e = p*256+tid
    const int e0 = tid, e1 = 256 + tid;
    const int r0 = e0>>2, r1 = e1>>2;
    const int cs0 = ((e0&3) ^ ((r0>>1)&3))*8;
    const int cs1 = ((e1&3) ^ ((r1>>1)&3))*8;

    auto stageB = [&](int kb, int buf){
        unsigned short* dst = smem + buf*8192;
        #pragma unroll
        for (int j=0; j<2; ++j){
            int k32 = 2*kb + j;
            int k = k32 % 7, scb = (k32/7)*32;
            const unsigned short* bb = Bsrc + ((size_t)(n*3350 + jn0 + 25*k))*384 + scb;
            stage16(bb + (size_t)r0*384 + cs0, dst + j*4096 + e0*8);
            stage16(bb + (size_t)r1*384 + cs1, dst + j*4096 + e1*8);
        }
    };

    // A row base pointers (L2-resident Wr, shared by all blocks)
    const unsigned short* arow0 = Amat + (size_t)(wm*64 + 0*16 + lr)*2688 + lg*8;
    const unsigned short* arow1 = Amat + (size_t)(wm*64 + 1*16 + lr)*2688 + lg*8;
    const unsigned short* arow2 = Amat + (size_t)(wm*64 + 2*16 + lr)*2688 + lg*8;
    const unsigned short* arow3 = Amat + (size_t)(wm*64 + 3*16 + lr)*2688 + lg*8;

    f32x4 acc[4][4];
    #pragma unroll
    for (int a2=0;a2<4;a2++)
        #pragma unroll
        for (int b2=0;b2<4;b2++) acc[a2][b2] = (f32x4){0.f,0.f,0.f,0.f};

    stageB(0, 0);
    stageB(1, 1);
    int bufc = 0, bufp = 2;
    for (int kb=0; kb<NKB; ++kb){
        if (kb < NKB-1) asm volatile("s_waitcnt vmcnt(4)" ::: "memory");
        else            asm volatile("s_waitcnt vmcnt(0)" ::: "memory");
        __builtin_amdgcn_s_barrier();
        asm volatile("" ::: "memory");
        const unsigned short* sB = smem + bufc*8192;
        s16x8 b[4][2];
        #pragma unroll
        for (int nf=0; nf<4; ++nf)
            #pragma unroll
            for (int kf=0; kf<2; ++kf)
                b[nf][kf] = *(const s16x8*)&sB[kf*4096 + (wn*64+nf*16+lr)*32 + swz];
        // A fragments from L2 (plain loads; compiler manages the waitcnt)
        s16x8 a[4][2];
        #pragma unroll
        for (int kf=0; kf<2; ++kf){
            a[0][kf] = *(const s16x8*)(arow0 + kb*64 + kf*32);
            a[1][kf] = *(const s16x8*)(arow1 + kb*64 + kf*32);
            a[2][kf] = *(const s16x8*)(arow2 + kb*64 + kf*32);
            a[3][kf] = *(const s16x8*)(arow3 + kb*64 + kf*32);
        }
        if (kb+2 < NKB) stageB(kb+2, bufp);
        __builtin_amdgcn_s_setprio(1);
        #pragma unroll
        for (int kf=0; kf<2; ++kf)
            #pragma unroll
            for (int mf=0; mf<4; ++mf)
                #pragma unroll
                for (int nf=0; nf<4; ++nf)
                    acc[mf][nf] = __builtin_amdgcn_mfma_f32_16x16x32_bf16(a[mf][kf], b[nf][kf], acc[mf][nf], 0, 0, 0);
        __builtin_amdgcn_s_setprio(0);
        bufc = (bufc==2) ? 0 : bufc+1;
        bufp = (bufp==2) ? 0 : bufp+1;
    }
    __syncthreads();

    float* wbl = (float*)(smem + 17408);
    float* asl = wbl + 2688;
    for (int i=tid; i<2688; i+=256) wbl[i] = wbpart[i];
    for (int i=tid; i<75;   i+=256) asl[i] = asum[n*75 + i];
    __syncthreads();

    #pragma unroll
    for (int nf=0; nf<4; ++nf){
        int cj = wn*64 + nf*16 + lr;
        int j  = jn0 + cj;
        int t  = j/25, v = j - t*25;
        int tc = (t<3) ? t : ((t>124) ? (t-121) : 3);
        float a0 = asl[v], a1 = asl[25+v], a2 = asl[50+v];
        #pragma unroll
        for (int mf=0; mf<4; ++mf)
            #pragma unroll
            for (int r=0; r<4; ++r){
                int m = wm*64 + mf*16 + lg*4 + r;
                float b2v = wbl[m*21+tc]*a0 + wbl[m*21+7+tc]*a1 + wbl[m*21+14+tc]*a2;
                float val = acc[mf][nf][r]*consts[m] + consts[128+m] + b2v
                          + xin[(size_t)n*409600 + (size_t)m*3200 + j];
                val = (val >= 0.f) ? val : 0.1f*val;
                smem[cj*136 + m] = f2bf(val);
            }
    }
    __syncthreads();

    f32x4 acc2[4][4];
    #pragma unroll
    for (int a2=0;a2<4;a2++)
        #pragma unroll
        for (int b2=0;b2<4;b2++) acc2[a2][b2] = (f32x4){0.f,0.f,0.f,0.f};
    #pragma unroll
    for (int kb2=0; kb2<4; ++kb2){
        s16x8 a2[4], b2[4];
        #pragma unroll
        for (int mf=0; mf<4; ++mf)
            a2[mf] = *(const s16x8*)&ffA[(size_t)(wm*64+mf*16+lr)*128 + kb2*32 + lg*8];
        #pragma unroll
        for (int nf=0; nf<4; ++nf)
            b2[nf] = *(const s16x8*)&smem[(wn*64+nf*16+lr)*136 + kb2*32 + lg*8];
        #pragma unroll
        for (int mf=0; mf<4; ++mf)
            #pragma unroll
            for (int nf=0; nf<4; ++nf)
                acc2[mf][nf] = __builtin_amdgcn_mfma_f32_16x16x32_bf16(a2[mf], b2[nf], acc2[mf][nf], 0, 0, 0);
    }

    #pragma unroll
    for (int mf=0; mf<4; ++mf)
        #pragma unroll
        for (int r=0; r<4; ++r){
            int co = wm*64 + mf*16 + lg*4 + r;
            float sc2 = consts[256+co], bi2 = consts[384+co];
            #pragma unroll
            for (int nf=0; nf<4; ++nf){
                int cj = wn*64 + nf*16 + lr;
                size_t idx = (size_t)n*409600 + (size_t)co*3200 + jn0 + cj;
                float val = acc2[mf][nf][r]*sc2 + bi2 + xin[idx];
                val = (val >= 0.f) ? val : 0.1f*val;
                outf[idx] = val;
            }
        }
}

extern "C" void kernel_launch(void* const* d_in, const int* in_sizes, int n_in,
                              void* d_out, int out_size, void* d_ws, size_t ws_size,
                              hipStream_t stream) {
    const float* x      = (const float*)d_in[0];
    const float* theta  = (const float*)d_in[1];
    const float* atts   = (const float*)d_in[2];
    const float* alphas = (const float*)d_in[3];
    const float* v_w    = (const float*)d_in[4];
    const float* v_b    = (const float*)d_in[5];
    const float* out_w  = (const float*)d_in[6];
    const float* out_b  = (const float*)d_in[7];
    const float* out_g  = (const float*)d_in[8];
    const float* out_be = (const float*)d_in[9];
    const float* out_m  = (const float*)d_in[10];
    const float* out_v  = (const float*)d_in[11];
    const float* ff_w   = (const float*)d_in[12];
    const float* ff_b   = (const float*)d_in[13];
    const float* ff_g   = (const float*)d_in[14];
    const float* ff_be  = (const float*)d_in[15];
    const float* ff_m   = (const float*)d_in[16];
    const float* ff_v   = (const float*)d_in[17];
    float* out = (float*)d_out;

    char* w = (char*)d_ws;
    size_t off = 0;
    auto alloc = [&](size_t b){ size_t r = off; off += (b + 1023) & ~(size_t)1023; return r; };
    float*          G      = (float*)         (w + alloc(160000));
    float*          asumb  = (float*)         (w + alloc(19200));
    float*          consts = (float*)         (w + alloc(2048));
    float*          wbpart = (float*)         (w + alloc(10752));
    float*          pebg   = (float*)         (w + alloc(12800));
    float*          TPgb   = (float*)         (w + alloc(2500));
    unsigned short* att_pad= (unsigned short*)(w + alloc(327680));
    unsigned short* Wr     = (unsigned short*)(w + alloc(688128));
    unsigned short* ffA    = (unsigned short*)(w + alloc(32768));
    unsigned short* xbt    = (unsigned short*)(w + alloc(52428800 + 16384));
    unsigned short* xbu    = (unsigned short*)(w + alloc(67108864));
    unsigned short* ypad   = (unsigned short*)(w + alloc(164659200));

    hipMemsetAsync(xbu, 0, 67108864, stream);
    prep_kernel<<<2048,256,0,stream>>>(out_w, ff_w, v_b, out_b, out_g, out_be, out_m, out_v,
                                       ff_b, ff_g, ff_be, ff_m, ff_v,
                                       consts, ffA, ypad, wbpart, pebg, TPgb);
    wfold_kernel<<<896,384,0,stream>>>(out_w, v_w, Wr);
    xt_kernel<<<6400,256,0,stream>>>(x, xbt, xbu);
    gram_mfma<<<64,256,0,stream>>>(xbt, pebg, TPgb, G);
    attn_kernel<<<1,1024,0,stream>>>(G, theta, atts, alphas, att_pad, asumb);
    agg_mfma<<<1024,256,0,stream>>>(att_pad, xbu, ypad);
    gemm_fused<<<1600,256,0,stream>>>(Wr, ypad, x, consts, ffA, wbpart, asumb, out);
}

// Round 9
// 624.931 us; speedup vs baseline: 1.2979x; 1.2979x over previous
//
#include <hip/hip_runtime.h>
#include <hip/hip_bf16.h>
#include <math.h>

typedef __attribute__((ext_vector_type(8))) short s16x8;
typedef __attribute__((ext_vector_type(4))) float f32x4;

static __device__ __forceinline__ float bf2f(unsigned short u){
    unsigned int x = ((unsigned int)u) << 16; float f; __builtin_memcpy(&f,&x,4); return f;
}
static __device__ __forceinline__ unsigned short f2bf(float f){
    unsigned int x; __builtin_memcpy(&x,&f,4);
    unsigned int r = (x + 0x7FFFu + ((x>>16)&1u)) >> 16; return (unsigned short)r;
}

static __device__ __forceinline__ void stage16(const void* g, void* l){
    __builtin_amdgcn_global_load_lds((const __attribute__((address_space(1))) unsigned int*)g,
                                     (__attribute__((address_space(3))) unsigned int*)l, 16, 0, 0);
}

// ---------------- sizes ----------------
// N=64, C=128, T=128, V=25, S=3, K=7
// JN = 3200, NTV = 204800, PADROW = 3350, K-dim = 384*7 = 2688

// ---------------- setup: xt (blocks 0..6399) + wfold (6400..7295) + prep (7296..9343) ----------------
__global__ __launch_bounds__(256) void setup_kernel(const float* __restrict__ x,
                            const float* __restrict__ out_w, const float* __restrict__ ff_w,
                            const float* __restrict__ v_w,  const float* __restrict__ v_b,
                            const float* __restrict__ out_b, const float* __restrict__ out_g,
                            const float* __restrict__ out_be, const float* __restrict__ out_m,
                            const float* __restrict__ out_v,
                            const float* __restrict__ ff_b, const float* __restrict__ ff_g,
                            const float* __restrict__ ff_be, const float* __restrict__ ff_m,
                            const float* __restrict__ ff_v,
                            float* __restrict__ consts, unsigned short* __restrict__ ffA,
                            unsigned short* __restrict__ ypad, float* __restrict__ wbpart,
                            float* __restrict__ pebg, float* __restrict__ TPgb,
                            unsigned short* __restrict__ Wr,
                            unsigned short* __restrict__ xbt, unsigned short* __restrict__ xbu)
{
    __shared__ float tile[64][65];
    const int bid = blockIdx.x;
    const int tid = threadIdx.x;

    if (bid < 6400){
        // ---- x transpose + xbu emit ----
        int jb = bid % 50; int cb = (bid/50) & 1; int n = bid/100;
        int lane = tid & 63, wv = tid >> 6;
        size_t xbase = (size_t)n*409600;
        int jn = jb*64 + lane;
        int tt = jn/25, uu = jn - tt*25;
        size_t xbu_lb = (size_t)n*524288 + (size_t)tt*4096 + uu;
        #pragma unroll
        for (int r=wv; r<64; r+=4){
            float v = x[xbase + (size_t)(cb*64+r)*3200 + jb*64 + lane];
            tile[r][lane] = v;
            xbu[xbu_lb + (size_t)(cb*64+r)*32] = f2bf(v);
        }
        __syncthreads();
        #pragma unroll
        for (int j=wv; j<64; j+=4)
            xbt[xbase + (size_t)(jb*64+j)*128 + cb*64 + lane] = f2bf(tile[lane][j]);
        return;
    }

    if (bid < 7296){
        // ---- wfold: Wr[o][(s,ci),k packed] = sum_c out_w[o,(s,c),k] * v_w[c,ci] ----
        float* owl = &tile[0][0];    // 384 floats
        int wb = bid - 6400;
        int o = wb/7, k = wb%7;
        for (int i=tid; i<384; i+=256) owl[i] = out_w[(size_t)(o*384 + i)*7 + k];
        __syncthreads();
        for (int sci=tid; sci<384; sci+=256){
            int s = sci >> 7, ci = sci & 127;
            const float* ow = owl + s*128;
            float acc = 0.f;
            #pragma unroll 8
            for (int c=0; c<128; ++c) acc += ow[c] * v_w[c*128 + ci];
            int kb = (sci>>5)*7 + k, jj = sci & 31;
            Wr[(size_t)o*2688 + kb*32 + jj] = f2bf(acc);
        }
        return;
    }

    // ---- prep ----
    const int stride = 2048*256;
    int i0 = (bid-7296)*256 + tid;
    const float KLN = 9.210340371976184f/128.f;   // ln(1e4)/C
    for (int i=i0; i<16384; i+=stride) ffA[i] = f2bf(ff_w[i]);
    for (int i=i0; i<128; i+=stride){
        float inv  = out_g[i]/sqrtf(out_v[i]+1e-5f);
        consts[i]       = inv;
        consts[128+i]   = out_b[i]*inv + out_be[i] - out_m[i]*inv;
        float invf = ff_g[i]/sqrtf(ff_v[i]+1e-5f);
        consts[256+i]   = invf;
        consts[384+i]   = ff_b[i]*invf + ff_be[i] - ff_m[i]*invf;
    }
    for (int i=i0; i<3200; i+=stride){
        int v = i >> 7, c = i & 127;
        float freq = expf(-(float)(c & ~1) * KLN);
        float ang = (float)v * freq;
        pebg[i] = (c & 1) ? cosf(ang) : sinf(ang);
    }
    for (int i=i0; i<625; i+=stride){
        int u = i/25, v = i%25;
        float acc = 0.f;
        for (int c=0; c<128; ++c){
            float freq = expf(-(float)(c & ~1) * KLN);
            float pu = (c & 1) ? cosf((float)u*freq) : sinf((float)u*freq);
            float pv = (c & 1) ? cosf((float)v*freq) : sinf((float)v*freq);
            acc += pu*pv;
        }
        TPgb[i] = 128.f*acc;
    }
    // wbpart[o][s][tc]
    for (int i=i0; i<2688; i+=stride){
        int o = i/21, rem = i%21, s = rem/7, tc = rem%7;
        int kmin = (tc<3) ? (3-tc) : 0;
        int kmax = (tc>3) ? (10-tc) : 7;
        float acc = 0.f;
        for (int c=0; c<128; ++c){
            const float* wp = out_w + (size_t)(o*384 + s*128 + c)*7;
            float vb = v_b[c];
            for (int k=kmin; k<kmax; ++k) acc += wp[k]*vb;
        }
        wbpart[i] = acc;
    }
    // zero the temporal halo pads of Ypad
    for (int i=i0; i<3686400; i+=stride){
        int n2 = i/57600, r2 = i%57600;
        int pp = r2/384, sc = r2%384;
        int ppos = (pp < 75) ? pp : (3200 + pp);
        ypad[(size_t)(n2*3350 + ppos)*384 + sc] = 0;
    }
    // zero the u-pads of xbu: [n][t][c][25..31]
    for (int i=i0; i<7340032; i+=stride){
        int n2 = i/114688, rem = i%114688;
        int t = rem/896, r2 = rem%896;
        int c = r2/7, u = 25 + r2%7;
        xbu[(size_t)n2*524288 + (size_t)t*4096 + c*32 + u] = 0;
    }
}

// ---------------- gram via MFMA ----------------
__global__ __launch_bounds__(256) void gram_mfma(const unsigned short* __restrict__ xbt,
                                                 const float* __restrict__ pebg,
                                                 const float* __restrict__ TPgb,
                                                 float* __restrict__ G){
    __shared__ float sxl[25][129];
    __shared__ float pebl[25][129];
    __shared__ float glx[4][32][32];
    int n = blockIdx.x, tid = threadIdx.x;
    const unsigned short* xb = xbt + (size_t)n*409600;

    int c = tid & 127, th = tid >> 7;
    float a[25];
    #pragma unroll
    for (int u=0; u<25; ++u) a[u] = 0.f;
    for (int tt=0; tt<64; ++tt){
        const unsigned short* row = xb + (size_t)(th*64+tt)*3200 + c;
        #pragma unroll
        for (int u=0; u<25; ++u) a[u] += bf2f(row[u*128]);
    }
    float* tmp = &glx[0][0][0];
    if (th){
        #pragma unroll
        for (int u=0; u<25; ++u) tmp[u*128+c] = a[u];
    }
    __syncthreads();
    if (!th){
        #pragma unroll
        for (int u=0; u<25; ++u) sxl[u][c] = a[u] + tmp[u*128+c];
    }
    for (int i=tid; i<3200; i+=256) pebl[i>>7][i&127] = pebg[i];
    __syncthreads();

    int lane = tid & 63, w = tid >> 6;
    int lr = lane & 15, lg = lane >> 4;
    f32x4 acc[2][2];
    #pragma unroll
    for (int i2=0;i2<2;i2++)
        #pragma unroll
        for (int j2=0;j2<2;j2++) acc[i2][j2] = (f32x4){0.f,0.f,0.f,0.f};
    for (int tt=0; tt<32; ++tt){
        int t = tt*4 + w;
        const unsigned short* tb = xb + (size_t)t*3200;
        #pragma unroll
        for (int kc=0; kc<4; ++kc){
            s16x8 f0 = *(const s16x8*)(tb + (size_t)(lr)*128      + kc*32 + lg*8);
            s16x8 f1 = *(const s16x8*)(tb + (size_t)(16+lr)*128   + kc*32 + lg*8);
            acc[0][0] = __builtin_amdgcn_mfma_f32_16x16x32_bf16(f0, f0, acc[0][0], 0,0,0);
            acc[0][1] = __builtin_amdgcn_mfma_f32_16x16x32_bf16(f0, f1, acc[0][1], 0,0,0);
            acc[1][0] = __builtin_amdgcn_mfma_f32_16x16x32_bf16(f1, f0, acc[1][0], 0,0,0);
            acc[1][1] = __builtin_amdgcn_mfma_f32_16x16x32_bf16(f1, f1, acc[1][1], 0,0,0);
        }
    }
    __syncthreads();
    #pragma unroll
    for (int mh=0; mh<2; ++mh)
        #pragma unroll
        for (int nh=0; nh<2; ++nh)
            #pragma unroll
            for (int r=0; r<4; ++r)
                glx[w][mh*16 + lg*4 + r][nh*16 + lr] = acc[mh][nh][r];
    __syncthreads();

    for (int idx=tid; idx<625; idx+=256){
        int u = idx/25, v = idx%25;
        float gx = glx[0][u][v] + glx[1][u][v] + glx[2][u][v] + glx[3][u][v];
        float cr = TPgb[idx];
        #pragma unroll 4
        for (int cc=0; cc<128; ++cc)
            cr += sxl[u][cc]*pebl[v][cc] + sxl[v][cc]*pebl[u][cc];
        G[n*625 + idx] = gx + cr;
    }
}

// ---------------- attention ----------------
__global__ __launch_bounds__(1024) void attn_kernel(const float* __restrict__ G, const float* __restrict__ theta,
                                                    const float* __restrict__ atts, const float* __restrict__ alphas,
                                                    unsigned short* __restrict__ att_pad, float* __restrict__ asum){
    __shared__ float red[1024];
    int tid = threadIdx.x;
    float mx = 0.f;
    for (int idx=tid; idx<40000; idx+=1024){
        int n = idx/625, r = idx%625, u2 = r/25, v2 = r%25;
        const float* Gn = G + n*625;
        float d2v = fmaxf(Gn[u2*26] + Gn[v2*26] - 2.f*Gn[u2*25+v2], 0.f);
        mx = fmaxf(mx, d2v);
    }
    red[tid] = mx; __syncthreads();
    for (int s2=512; s2>0; s2>>=1){ if (tid < s2) red[tid] = fmaxf(red[tid], red[tid+s2]); __syncthreads(); }
    float inv = 1.f/red[0];
    for (int i=tid; i<64*160; i+=1024){
        int n2 = i/160, r2 = i%160;
        att_pad[n2*2560 + 2400 + r2] = 0;
    }
    for (int col=tid; col<4800; col+=1024){
        int n = col/75, r = col%75, s = r/25, vc = r%25;
        const float* Gn = G + n*625;
        float et = expf(theta[s]);
        float al = alphas[s];
        float gvv = Gn[vc*26];
        float z[25];
        #pragma unroll
        for (int u2=0; u2<25; ++u2){
            float d2v = fmaxf(Gn[u2*26] + gvv - 2.f*Gn[u2*25+vc], 0.f);
            z[u2] = expf(-et*d2v*inv);
        }
        float zm = z[0];
        #pragma unroll
        for (int u2=1; u2<25; ++u2) zm = fmaxf(zm, z[u2]);
        float lo = zm - 1.f, hi = zm;
        for (int it=0; it<30; ++it){
            float mid = 0.5f*(lo+hi);
            float f = 0.f;
            #pragma unroll
            for (int u2=0; u2<25; ++u2) f += fmaxf(z[u2]-mid, 0.f);
            if (f >= 1.f) lo = mid; else hi = mid;
        }
        float ssum = 0.f; int kcnt = 0;
        #pragma unroll
        for (int u2=0; u2<25; ++u2){ if (z[u2] > lo){ ssum += z[u2]; kcnt++; } }
        float tau = (ssum - 1.f)/(float)kcnt;
        float as_ = 0.f;
        unsigned short* apr = att_pad + n*2560 + (s*25+vc)*32;
        #pragma unroll
        for (int u2=0; u2<25; ++u2){
            float av = atts[s*625 + u2*25 + vc] + fmaxf(z[u2]-tau, 0.f)*al;
            apr[u2] = f2bf(av);
            as_ += av;
        }
        #pragma unroll
        for (int u2=25; u2<32; ++u2) apr[u2] = 0;
        asum[n*75 + s*25 + vc] = as_;
    }
}

// ---------------- agg via MFMA ----------------
__global__ __launch_bounds__(256,2) void agg_mfma(const unsigned short* __restrict__ att_pad,
                                                  const unsigned short* __restrict__ xbu,
                                                  unsigned short* __restrict__ ypad){
    int bid = blockIdx.x; int n = bid >> 4; int tb = bid & 15;
    int tid = threadIdx.x; int lane = tid & 63; int w = tid >> 6;
    int lr = lane & 15, lg = lane >> 4;
    const unsigned short* ap = att_pad + n*2560;
    s16x8 a[5];
    #pragma unroll
    for (int mf=0; mf<5; ++mf) a[mf] = *(const s16x8*)&ap[(mf*16+lr)*32 + lg*8];
    int rowoff[5][4];
    #pragma unroll
    for (int mf=0; mf<5; ++mf)
        #pragma unroll
        for (int r=0; r<4; ++r){
            int m = mf*16 + lg*4 + r;
            int s = m/25, v = m - s*25;
            rowoff[mf][r] = (m < 75) ? (v*384 + s*128 + lr) : -1;
        }
    #pragma unroll
    for (int ti=0; ti<2; ++ti){
        int t = tb*8 + w*2 + ti;
        const unsigned short* bp = xbu + (size_t)n*524288 + (size_t)t*4096;
        size_t obase = ((size_t)(n*3350 + 75 + t*25))*384;
        #pragma unroll
        for (int h=0; h<2; ++h){
            s16x8 b[4];
            #pragma unroll
            for (int q=0; q<4; ++q) b[q] = *(const s16x8*)&bp[(h*64 + q*16 + lr)*32 + lg*8];
            f32x4 acc[5][4];
            #pragma unroll
            for (int mf=0; mf<5; ++mf)
                #pragma unroll
                for (int q=0; q<4; ++q)
                    acc[mf][q] = (f32x4){0.f,0.f,0.f,0.f};
            #pragma unroll
            for (int mf=0; mf<5; ++mf)
                #pragma unroll
                for (int q=0; q<4; ++q)
                    acc[mf][q] = __builtin_amdgcn_mfma_f32_16x16x32_bf16(a[mf], b[q], acc[mf][q], 0, 0, 0);
            #pragma unroll
            for (int mf=0; mf<5; ++mf)
                #pragma unroll
                for (int q=0; q<4; ++q)
                    #pragma unroll
                    for (int r=0; r<4; ++r)
                        if (rowoff[mf][r] >= 0)
                            ypad[obase + rowoff[mf][r] + h*64 + q*16] = f2bf(acc[mf][q][r]);
        }
    }
}

// ---------------- fused conv+ff GEMM (R6 v2: BK=32, 3-deep counted-vmcnt, A+B staged) ----------------
__global__ __launch_bounds__(256,3) void gemm_fused(const unsigned short* __restrict__ Amat,
                                                    const unsigned short* __restrict__ Bsrc,
                                                    const float* __restrict__ xin,
                                                    const float* __restrict__ consts,
                                                    const unsigned short* __restrict__ ffA,
                                                    const float* __restrict__ wbpart,
                                                    const float* __restrict__ asum,
                                                    float* __restrict__ outf)
{
    constexpr int KTOT = 2688, NKB = 84;
    __shared__ unsigned short smem[24576];

    const int tid = threadIdx.x;
    const int bid = blockIdx.x;
    const int n   = bid/25;
    const int jn0 = (bid%25)*128;

    const int lane = tid & 63, wv = tid >> 6;
    const int wm = wv >> 1, wn = wv & 1;
    const int lr = lane & 15, lg = lane >> 4;
    const int swz = (lg ^ ((lr>>1)&3)) << 3;

    const int ga0 = tid, ga1 = 256 + tid;
    const int ra0 = ga0>>2, ra1 = ga1>>2;
    const int ca0 = ((ga0&3) ^ ((ra0>>1)&3))*8;
    const int ca1 = ((ga1&3) ^ ((ra1>>1)&3))*8;

    auto stage = [&](int kb, int buf){
        unsigned short* dst = smem + buf*8192;
        stage16(Amat + (size_t)ra0*KTOT + kb*32 + ca0, dst + ga0*8);
        stage16(Amat + (size_t)ra1*KTOT + kb*32 + ca1, dst + ga1*8);
        int k = kb%7, scb = (kb/7)*32;
        const unsigned short* bb = Bsrc + ((size_t)(n*3350 + jn0 + 25*k))*384 + scb;
        stage16(bb + (size_t)ra0*384 + ca0, dst + 4096 + ga0*8);
        stage16(bb + (size_t)ra1*384 + ca1, dst + 4096 + ga1*8);
    };

    f32x4 acc[4][4];
    #pragma unroll
    for (int a2=0;a2<4;a2++)
        #pragma unroll
        for (int b2=0;b2<4;b2++) acc[a2][b2] = (f32x4){0.f,0.f,0.f,0.f};

    stage(0, 0);
    stage(1, 1);
    int bufc = 0, bufp = 2;
    for (int kb=0; kb<NKB; ++kb){
        if (kb < NKB-1) asm volatile("s_waitcnt vmcnt(4)" ::: "memory");
        else            asm volatile("s_waitcnt vmcnt(0)" ::: "memory");
        __builtin_amdgcn_s_barrier();
        asm volatile("" ::: "memory");
        const unsigned short* sA = smem + bufc*8192;
        const unsigned short* sB = sA + 4096;
        s16x8 a[4], b[4];
        #pragma unroll
        for (int mf=0; mf<4; ++mf) a[mf] = *(const s16x8*)&sA[(wm*64+mf*16+lr)*32 + swz];
        #pragma unroll
        for (int nf=0; nf<4; ++nf) b[nf] = *(const s16x8*)&sB[(wn*64+nf*16+lr)*32 + swz];
        if (kb+2 < NKB) stage(kb+2, bufp);
        __builtin_amdgcn_s_setprio(1);
        #pragma unroll
        for (int mf=0; mf<4; ++mf)
            #pragma unroll
            for (int nf=0; nf<4; ++nf)
                acc[mf][nf] = __builtin_amdgcn_mfma_f32_16x16x32_bf16(a[mf], b[nf], acc[mf][nf], 0, 0, 0);
        __builtin_amdgcn_s_setprio(0);
        bufc = (bufc==2) ? 0 : bufc+1;
        bufp = (bufp==2) ? 0 : bufp+1;
    }
    __syncthreads();

    float* wbl = (float*)(smem + 17408);
    float* asl = wbl + 2688;
    for (int i=tid; i<2688; i+=256) wbl[i] = wbpart[i];
    for (int i=tid; i<75;   i+=256) asl[i] = asum[n*75 + i];
    __syncthreads();

    #pragma unroll
    for (int nf=0; nf<4; ++nf){
        int cj = wn*64 + nf*16 + lr;
        int j  = jn0 + cj;
        int t  = j/25, v = j - t*25;
        int tc = (t<3) ? t : ((t>124) ? (t-121) : 3);
        float a0 = asl[v], a1 = asl[25+v], a2 = asl[50+v];
        #pragma unroll
        for (int mf=0; mf<4; ++mf)
            #pragma unroll
            for (int r=0; r<4; ++r){
                int m = wm*64 + mf*16 + lg*4 + r;
                float b2v = wbl[m*21+tc]*a0 + wbl[m*21+7+tc]*a1 + wbl[m*21+14+tc]*a2;
                float val = acc[mf][nf][r]*consts[m] + consts[128+m] + b2v
                          + xin[(size_t)n*409600 + (size_t)m*3200 + j];
                val = (val >= 0.f) ? val : 0.1f*val;
                smem[cj*136 + m] = f2bf(val);
            }
    }
    __syncthreads();

    f32x4 acc2[4][4];
    #pragma unroll
    for (int a2=0;a2<4;a2++)
        #pragma unroll
        for (int b2=0;b2<4;b2++) acc2[a2][b2] = (f32x4){0.f,0.f,0.f,0.f};
    #pragma unroll
    for (int kb2=0; kb2<4; ++kb2){
        s16x8 a2[4], b2[4];
        #pragma unroll
        for (int mf=0; mf<4; ++mf)
            a2[mf] = *(const s16x8*)&ffA[(size_t)(wm*64+mf*16+lr)*128 + kb2*32 + lg*8];
        #pragma unroll
        for (int nf=0; nf<4; ++nf)
            b2[nf] = *(const s16x8*)&smem[(wn*64+nf*16+lr)*136 + kb2*32 + lg*8];
        #pragma unroll
        for (int mf=0; mf<4; ++mf)
            #pragma unroll
            for (int nf=0; nf<4; ++nf)
                acc2[mf][nf] = __builtin_amdgcn_mfma_f32_16x16x32_bf16(a2[mf], b2[nf], acc2[mf][nf], 0, 0, 0);
    }

    #pragma unroll
    for (int mf=0; mf<4; ++mf)
        #pragma unroll
        for (int r=0; r<4; ++r){
            int co = wm*64 + mf*16 + lg*4 + r;
            float sc2 = consts[256+co], bi2 = consts[384+co];
            #pragma unroll
            for (int nf=0; nf<4; ++nf){
                int cj = wn*64 + nf*16 + lr;
                size_t idx = (size_t)n*409600 + (size_t)co*3200 + jn0 + cj;
                float val = acc2[mf][nf][r]*sc2 + bi2 + xin[idx];
                val = (val >= 0.f) ? val : 0.1f*val;
                outf[idx] = val;
            }
        }
}

extern "C" void kernel_launch(void* const* d_in, const int* in_sizes, int n_in,
                              void* d_out, int out_size, void* d_ws, size_t ws_size,
                              hipStream_t stream) {
    const float* x      = (const float*)d_in[0];
    const float* theta  = (const float*)d_in[1];
    const float* atts   = (const float*)d_in[2];
    const float* alphas = (const float*)d_in[3];
    const float* v_w    = (const float*)d_in[4];
    const float* v_b    = (const float*)d_in[5];
    const float* out_w  = (const float*)d_in[6];
    const float* out_b  = (const float*)d_in[7];
    const float* out_g  = (const float*)d_in[8];
    const float* out_be = (const float*)d_in[9];
    const float* out_m  = (const float*)d_in[10];
    const float* out_v  = (const float*)d_in[11];
    const float* ff_w   = (const float*)d_in[12];
    const float* ff_b   = (const float*)d_in[13];
    const float* ff_g   = (const float*)d_in[14];
    const float* ff_be  = (const float*)d_in[15];
    const float* ff_m   = (const float*)d_in[16];
    const float* ff_v   = (const float*)d_in[17];
    float* out = (float*)d_out;

    char* w = (char*)d_ws;
    size_t off = 0;
    auto alloc = [&](size_t b){ size_t r = off; off += (b + 1023) & ~(size_t)1023; return r; };
    float*          G      = (float*)         (w + alloc(160000));
    float*          asumb  = (float*)         (w + alloc(19200));
    float*          consts = (float*)         (w + alloc(2048));
    float*          wbpart = (float*)         (w + alloc(10752));
    float*          pebg   = (float*)         (w + alloc(12800));
    float*          TPgb   = (float*)         (w + alloc(2500));
    unsigned short* att_pad= (unsigned short*)(w + alloc(327680));
    unsigned short* Wr     = (unsigned short*)(w + alloc(688128));
    unsigned short* ffA    = (unsigned short*)(w + alloc(32768));
    unsigned short* xbt    = (unsigned short*)(w + alloc(52428800 + 16384));
    unsigned short* xbu    = (unsigned short*)(w + alloc(67108864));
    unsigned short* ypad   = (unsigned short*)(w + alloc(164659200));

    setup_kernel<<<9344,256,0,stream>>>(x, out_w, ff_w, v_w, v_b, out_b, out_g, out_be, out_m, out_v,
                                        ff_b, ff_g, ff_be, ff_m, ff_v,
                                        consts, ffA, ypad, wbpart, pebg, TPgb, Wr, xbt, xbu);
    gram_mfma<<<64,256,0,stream>>>(xbt, pebg, TPgb, G);
    attn_kernel<<<1,1024,0,stream>>>(G, theta, atts, alphas, att_pad, asumb);
    agg_mfma<<<1024,256,0,stream>>>(att_pad, xbu, ypad);
    gemm_fused<<<1600,256,0,stream>>>(Wr, ypad, x, consts, ffA, wbpart, asumb, out);
}

// Round 10
// 573.637 us; speedup vs baseline: 1.4139x; 1.0894x over previous
//
#include <hip/hip_runtime.h>
#include <hip/hip_bf16.h>
#include <math.h>

typedef __attribute__((ext_vector_type(8))) short s16x8;
typedef __attribute__((ext_vector_type(4))) float f32x4;

static __device__ __forceinline__ float bf2f(unsigned short u){
    unsigned int x = ((unsigned int)u) << 16; float f; __builtin_memcpy(&f,&x,4); return f;
}
static __device__ __forceinline__ unsigned short f2bf(float f){
    unsigned int x; __builtin_memcpy(&x,&f,4);
    unsigned int r = (x + 0x7FFFu + ((x>>16)&1u)) >> 16; return (unsigned short)r;
}

static __device__ __forceinline__ void stage16(const void* g, void* l){
    __builtin_amdgcn_global_load_lds((const __attribute__((address_space(1))) unsigned int*)g,
                                     (__attribute__((address_space(3))) unsigned int*)l, 16, 0, 0);
}

// ---------------- sizes ----------------
// N=64, C=128, T=128, V=25, S=3, K=7
// JN = 3200, NTV = 204800, PADROW = 3350, K-dim = 384*7 = 2688

// ---------------- setup: xt (0..6399) + wfold (6400..7295) + prep (7296..9343) ----------------
__global__ __launch_bounds__(256) void setup_kernel(const float* __restrict__ x,
                            const float* __restrict__ out_w, const float* __restrict__ ff_w,
                            const float* __restrict__ v_w,  const float* __restrict__ v_b,
                            const float* __restrict__ out_b, const float* __restrict__ out_g,
                            const float* __restrict__ out_be, const float* __restrict__ out_m,
                            const float* __restrict__ out_v,
                            const float* __restrict__ ff_b, const float* __restrict__ ff_g,
                            const float* __restrict__ ff_be, const float* __restrict__ ff_m,
                            const float* __restrict__ ff_v,
                            float* __restrict__ consts, unsigned short* __restrict__ ffA,
                            unsigned short* __restrict__ ypad, float* __restrict__ wbpart,
                            float* __restrict__ pebg, float* __restrict__ TPgb,
                            unsigned short* __restrict__ Wr,
                            unsigned short* __restrict__ xbt, unsigned short* __restrict__ xbu,
                            float* __restrict__ G, float* __restrict__ SX)
{
    __shared__ float tile[64][65];
    const int bid = blockIdx.x;
    const int tid = threadIdx.x;

    if (bid < 6400){
        int jb = bid % 50; int cb = (bid/50) & 1; int n = bid/100;
        int lane = tid & 63, wv = tid >> 6;
        size_t xbase = (size_t)n*409600;
        int jn = jb*64 + lane;
        int tt = jn/25, uu = jn - tt*25;
        size_t xbu_lb = (size_t)n*524288 + (size_t)tt*4096 + uu;
        #pragma unroll
        for (int r=wv; r<64; r+=4){
            float v = x[xbase + (size_t)(cb*64+r)*3200 + jb*64 + lane];
            tile[r][lane] = v;
            xbu[xbu_lb + (size_t)(cb*64+r)*32] = f2bf(v);
        }
        __syncthreads();
        #pragma unroll
        for (int j=wv; j<64; j+=4)
            xbt[xbase + (size_t)(jb*64+j)*128 + cb*64 + lane] = f2bf(tile[lane][j]);
        return;
    }

    if (bid < 7296){
        float* owl = &tile[0][0];
        int wb = bid - 6400;
        int o = wb/7, k = wb%7;
        for (int i=tid; i<384; i+=256) owl[i] = out_w[(size_t)(o*384 + i)*7 + k];
        __syncthreads();
        for (int sci=tid; sci<384; sci+=256){
            int s = sci >> 7, ci = sci & 127;
            const float* ow = owl + s*128;
            float acc = 0.f;
            #pragma unroll 8
            for (int c=0; c<128; ++c) acc += ow[c] * v_w[c*128 + ci];
            int kb = (sci>>5)*7 + k, jj = sci & 31;
            Wr[(size_t)o*2688 + kb*32 + jj] = f2bf(acc);
        }
        return;
    }

    // ---- prep ----
    const int stride = 2048*256;
    int i0 = (bid-7296)*256 + tid;
    const float KLN = 9.210340371976184f/128.f;   // ln(1e4)/C
    for (int i=i0; i<40000;  i+=stride) G[i]  = 0.f;
    for (int i=i0; i<204800; i+=stride) SX[i] = 0.f;
    for (int i=i0; i<16384; i+=stride) ffA[i] = f2bf(ff_w[i]);
    for (int i=i0; i<128; i+=stride){
        float inv  = out_g[i]/sqrtf(out_v[i]+1e-5f);
        consts[i]       = inv;
        consts[128+i]   = out_b[i]*inv + out_be[i] - out_m[i]*inv;
        float invf = ff_g[i]/sqrtf(ff_v[i]+1e-5f);
        consts[256+i]   = invf;
        consts[384+i]   = ff_b[i]*invf + ff_be[i] - ff_m[i]*invf;
    }
    for (int i=i0; i<3200; i+=stride){
        int v = i >> 7, c = i & 127;
        float freq = expf(-(float)(c & ~1) * KLN);
        float ang = (float)v * freq;
        pebg[i] = (c & 1) ? cosf(ang) : sinf(ang);
    }
    for (int i=i0; i<625; i+=stride){
        int u = i/25, v = i%25;
        float acc = 0.f;
        for (int c=0; c<128; ++c){
            float freq = expf(-(float)(c & ~1) * KLN);
            float pu = (c & 1) ? cosf((float)u*freq) : sinf((float)u*freq);
            float pv = (c & 1) ? cosf((float)v*freq) : sinf((float)v*freq);
            acc += pu*pv;
        }
        TPgb[i] = 128.f*acc;
    }
    for (int i=i0; i<2688; i+=stride){
        int o = i/21, rem = i%21, s = rem/7, tc = rem%7;
        int kmin = (tc<3) ? (3-tc) : 0;
        int kmax = (tc>3) ? (10-tc) : 7;
        float acc = 0.f;
        for (int c=0; c<128; ++c){
            const float* wp = out_w + (size_t)(o*384 + s*128 + c)*7;
            float vb = v_b[c];
            for (int k=kmin; k<kmax; ++k) acc += wp[k]*vb;
        }
        wbpart[i] = acc;
    }
    // zero the temporal halo pads of Ypad
    for (int i=i0; i<3686400; i+=stride){
        int n2 = i/57600, r2 = i%57600;
        int pp = r2/384, sc = r2%384;
        int ppos = (pp < 75) ? pp : (3200 + pp);
        ypad[(size_t)(n2*3350 + ppos)*384 + sc] = 0;
    }
    // NOTE: xbu u-pads (u=25..31) left as garbage; agg_mfma masks them in-register.
}

// ---------------- gram part: partial Gx (MFMA) + partial sx, atomics, 512 blocks ----------------
__global__ __launch_bounds__(256) void gram_part(const unsigned short* __restrict__ xbt,
                                                 float* __restrict__ G, float* __restrict__ SX){
    __shared__ float glx[4][32][32];
    int bid = blockIdx.x; int n = bid >> 3; int chunk = bid & 7;
    int tid = threadIdx.x;
    const unsigned short* xb = xbt + (size_t)n*409600;

    // phase A: partial sx over this block's 16 t values
    int c = tid & 127, th = tid >> 7;
    float a[25];
    #pragma unroll
    for (int u=0; u<25; ++u) a[u] = 0.f;
    for (int tt=0; tt<8; ++tt){
        int t = chunk*16 + th*8 + tt;
        const unsigned short* row = xb + (size_t)t*3200 + c;
        #pragma unroll
        for (int u=0; u<25; ++u) a[u] += bf2f(row[u*128]);
    }
    float* tmp = &glx[0][0][0];
    if (th){
        #pragma unroll
        for (int u=0; u<25; ++u) tmp[u*128+c] = a[u];
    }
    __syncthreads();
    if (!th){
        #pragma unroll
        for (int u=0; u<25; ++u) atomicAdd(&SX[n*3200 + u*128 + c], a[u] + tmp[u*128+c]);
    }
    __syncthreads();   // tmp fully consumed before phase B reuses glx

    // phase B: partial Gx via MFMA over 16 t (4 waves x 4 t)
    int lane = tid & 63, w = tid >> 6;
    int lr = lane & 15, lg = lane >> 4;
    f32x4 acc[2][2];
    #pragma unroll
    for (int i2=0;i2<2;i2++)
        #pragma unroll
        for (int j2=0;j2<2;j2++) acc[i2][j2] = (f32x4){0.f,0.f,0.f,0.f};
    for (int tt=0; tt<4; ++tt){
        int t = chunk*16 + w*4 + tt;
        const unsigned short* tb = xb + (size_t)t*3200;
        #pragma unroll
        for (int kc=0; kc<4; ++kc){
            s16x8 f0 = *(const s16x8*)(tb + (size_t)(lr)*128    + kc*32 + lg*8);
            s16x8 f1 = *(const s16x8*)(tb + (size_t)(16+lr)*128 + kc*32 + lg*8);
            acc[0][0] = __builtin_amdgcn_mfma_f32_16x16x32_bf16(f0, f0, acc[0][0], 0,0,0);
            acc[0][1] = __builtin_amdgcn_mfma_f32_16x16x32_bf16(f0, f1, acc[0][1], 0,0,0);
            acc[1][0] = __builtin_amdgcn_mfma_f32_16x16x32_bf16(f1, f0, acc[1][0], 0,0,0);
            acc[1][1] = __builtin_amdgcn_mfma_f32_16x16x32_bf16(f1, f1, acc[1][1], 0,0,0);
        }
    }
    #pragma unroll
    for (int mh=0; mh<2; ++mh)
        #pragma unroll
        for (int nh=0; nh<2; ++nh)
            #pragma unroll
            for (int r=0; r<4; ++r)
                glx[w][mh*16 + lg*4 + r][nh*16 + lr] = acc[mh][nh][r];
    __syncthreads();
    for (int idx=tid; idx<625; idx+=256){
        int u = idx/25, v = idx%25;
        atomicAdd(&G[n*625 + idx], glx[0][u][v] + glx[1][u][v] + glx[2][u][v] + glx[3][u][v]);
    }
}

// ---------------- gram fin: G += pe correction ----------------
__global__ __launch_bounds__(256) void gram_fin(const float* __restrict__ SX,
                                                const float* __restrict__ pebg,
                                                const float* __restrict__ TPgb,
                                                float* __restrict__ G){
    __shared__ float sxl[25][129];
    __shared__ float pebl[25][129];
    int n = blockIdx.x, tid = threadIdx.x;
    for (int i=tid; i<3200; i+=256){
        sxl[i>>7][i&127]  = SX[n*3200 + i];
        pebl[i>>7][i&127] = pebg[i];
    }
    __syncthreads();
    for (int idx=tid; idx<625; idx+=256){
        int u = idx/25, v = idx%25;
        float cr = TPgb[idx];
        #pragma unroll 4
        for (int cc=0; cc<128; ++cc)
            cr += sxl[u][cc]*pebl[v][cc] + sxl[v][cc]*pebl[u][cc];
        G[n*625 + idx] += cr;
    }
}

// ---------------- attention ----------------
__global__ __launch_bounds__(1024) void attn_kernel(const float* __restrict__ G, const float* __restrict__ theta,
                                                    const float* __restrict__ atts, const float* __restrict__ alphas,
                                                    unsigned short* __restrict__ att_pad, float* __restrict__ asum){
    __shared__ float red[1024];
    int tid = threadIdx.x;
    float mx = 0.f;
    for (int idx=tid; idx<40000; idx+=1024){
        int n = idx/625, r = idx%625, u2 = r/25, v2 = r%25;
        const float* Gn = G + n*625;
        float d2v = fmaxf(Gn[u2*26] + Gn[v2*26] - 2.f*Gn[u2*25+v2], 0.f);
        mx = fmaxf(mx, d2v);
    }
    red[tid] = mx; __syncthreads();
    for (int s2=512; s2>0; s2>>=1){ if (tid < s2) red[tid] = fmaxf(red[tid], red[tid+s2]); __syncthreads(); }
    float inv = 1.f/red[0];
    for (int i=tid; i<64*160; i+=1024){
        int n2 = i/160, r2 = i%160;
        att_pad[n2*2560 + 2400 + r2] = 0;
    }
    for (int col=tid; col<4800; col+=1024){
        int n = col/75, r = col%75, s = r/25, vc = r%25;
        const float* Gn = G + n*625;
        float et = expf(theta[s]);
        float al = alphas[s];
        float gvv = Gn[vc*26];
        float z[25];
        #pragma unroll
        for (int u2=0; u2<25; ++u2){
            float d2v = fmaxf(Gn[u2*26] + gvv - 2.f*Gn[u2*25+vc], 0.f);
            z[u2] = expf(-et*d2v*inv);
        }
        float zm = z[0];
        #pragma unroll
        for (int u2=1; u2<25; ++u2) zm = fmaxf(zm, z[u2]);
        float lo = zm - 1.f, hi = zm;
        for (int it=0; it<30; ++it){
            float mid = 0.5f*(lo+hi);
            float f = 0.f;
            #pragma unroll
            for (int u2=0; u2<25; ++u2) f += fmaxf(z[u2]-mid, 0.f);
            if (f >= 1.f) lo = mid; else hi = mid;
        }
        float ssum = 0.f; int kcnt = 0;
        #pragma unroll
        for (int u2=0; u2<25; ++u2){ if (z[u2] > lo){ ssum += z[u2]; kcnt++; } }
        float tau = (ssum - 1.f)/(float)kcnt;
        float as_ = 0.f;
        unsigned short* apr = att_pad + n*2560 + (s*25+vc)*32;
        #pragma unroll
        for (int u2=0; u2<25; ++u2){
            float av = atts[s*625 + u2*25 + vc] + fmaxf(z[u2]-tau, 0.f)*al;
            apr[u2] = f2bf(av);
            as_ += av;
        }
        #pragma unroll
        for (int u2=25; u2<32; ++u2) apr[u2] = 0;
        asum[n*75 + s*25 + vc] = as_;
    }
}

// ---------------- agg via MFMA (xbu u-pads masked in-register) ----------------
__global__ __launch_bounds__(256,2) void agg_mfma(const unsigned short* __restrict__ att_pad,
                                                  const unsigned short* __restrict__ xbu,
                                                  unsigned short* __restrict__ ypad){
    int bid = blockIdx.x; int n = bid >> 4; int tb = bid & 15;
    int tid = threadIdx.x; int lane = tid & 63; int w = tid >> 6;
    int lr = lane & 15, lg = lane >> 4;
    const unsigned short* ap = att_pad + n*2560;
    s16x8 a[5];
    #pragma unroll
    for (int mf=0; mf<5; ++mf) a[mf] = *(const s16x8*)&ap[(mf*16+lr)*32 + lg*8];
    int rowoff[5][4];
    #pragma unroll
    for (int mf=0; mf<5; ++mf)
        #pragma unroll
        for (int r=0; r<4; ++r){
            int m = mf*16 + lg*4 + r;
            int s = m/25, v = m - s*25;
            rowoff[mf][r] = (m < 75) ? (v*384 + s*128 + lr) : -1;
        }
    #pragma unroll
    for (int ti=0; ti<2; ++ti){
        int t = tb*8 + w*2 + ti;
        const unsigned short* bp = xbu + (size_t)n*524288 + (size_t)t*4096;
        size_t obase = ((size_t)(n*3350 + 75 + t*25))*384;
        #pragma unroll
        for (int h=0; h<2; ++h){
            s16x8 b[4];
            #pragma unroll
            for (int q=0; q<4; ++q){
                b[q] = *(const s16x8*)&bp[(h*64 + q*16 + lr)*32 + lg*8];
                if (lg == 3){
                    s16x8 t2 = b[q];
                    b[q] = (s16x8){t2[0],0,0,0,0,0,0,0};   // u=24 real; u=25..31 pad masked
                }
            }
            f32x4 acc[5][4];
            #pragma unroll
            for (int mf=0; mf<5; ++mf)
                #pragma unroll
                for (int q=0; q<4; ++q)
                    acc[mf][q] = (f32x4){0.f,0.f,0.f,0.f};
            #pragma unroll
            for (int mf=0; mf<5; ++mf)
                #pragma unroll
                for (int q=0; q<4; ++q)
                    acc[mf][q] = __builtin_amdgcn_mfma_f32_16x16x32_bf16(a[mf], b[q], acc[mf][q], 0, 0, 0);
            #pragma unroll
            for (int mf=0; mf<5; ++mf)
                #pragma unroll
                for (int q=0; q<4; ++q)
                    #pragma unroll
                    for (int r=0; r<4; ++r)
                        if (rowoff[mf][r] >= 0)
                            ypad[obase + rowoff[mf][r] + h*64 + q*16] = f2bf(acc[mf][q][r]);
        }
    }
}

// ---------------- fused conv+ff GEMM v4: m97 structure — BK=64, single buffer, 32 MFMA/step ----------------
__global__ __launch_bounds__(256,3) void gemm_fused(const unsigned short* __restrict__ Amat,
                                                    const unsigned short* __restrict__ Bsrc,
                                                    const float* __restrict__ xin,
                                                    const float* __restrict__ consts,
                                                    const unsigned short* __restrict__ ffA,
                                                    const float* __restrict__ wbpart,
                                                    const float* __restrict__ asum,
                                                    float* __restrict__ outf)
{
    constexpr int NKB = 42;                   // 42 K-steps of BK=64
    __shared__ unsigned short smem[22936];    // A(128x64)+B(128x64)=32KB; epilogue needs 45868B

    const int tid = threadIdx.x;
    const int bid = blockIdx.x;
    const int n   = bid/25;
    const int jn0 = (bid%25)*128;

    const int lane = tid & 63, wv = tid >> 6;
    const int wm = wv >> 1, wn = wv & 1;
    const int lr = lane & 15, lg = lane >> 4;
    const int swz = (lg ^ (lr&3)) << 3;       // read swizzle within each 32-short half

    unsigned short* sA = smem;
    unsigned short* sB = smem + 8192;

    auto stage = [&](int kb){
        // A: rows 0..127 x 64 shorts; chunk e: r=e>>3, cch=e&7; half=cch>>2; src col-chunk=(cch&3)^(r&3)
        #pragma unroll
        for (int p=0; p<4; ++p){
            int e = p*256 + tid;
            int r = e >> 3, cch = e & 7;
            int half = cch >> 2, cc = (cch&3) ^ (r&3);
            stage16(Amat + (size_t)r*2688 + kb*64 + half*32 + cc*8, sA + e*8);
        }
        int k32a = 2*kb, k32b = 2*kb + 1;
        int k0 = k32a % 7, s0 = (k32a/7)*32;
        int k1 = k32b % 7, s1 = (k32b/7)*32;
        const unsigned short* b0 = Bsrc + ((size_t)(n*3350 + jn0 + 25*k0))*384 + s0;
        const unsigned short* b1 = Bsrc + ((size_t)(n*3350 + jn0 + 25*k1))*384 + s1;
        #pragma unroll
        for (int p=0; p<4; ++p){
            int e = p*256 + tid;
            int r = e >> 3, cch = e & 7;
            int half = cch >> 2, cc = (cch&3) ^ (r&3);
            const unsigned short* src = (half ? b1 : b0) + (size_t)r*384 + cc*8;
            stage16(src, sB + e*8);
        }
    };

    f32x4 acc[4][4];
    #pragma unroll
    for (int a2=0;a2<4;a2++)
        #pragma unroll
        for (int b2=0;b2<4;b2++) acc[a2][b2] = (f32x4){0.f,0.f,0.f,0.f};

    for (int kb=0; kb<NKB; ++kb){
        stage(kb);
        __syncthreads();                       // drains vmcnt(0): staged tile visible to all
        s16x8 a[4][2], b[4][2];
        #pragma unroll
        for (int mf=0; mf<4; ++mf)
            #pragma unroll
            for (int kf=0; kf<2; ++kf)
                a[mf][kf] = *(const s16x8*)&sA[(wm*64+mf*16+lr)*64 + kf*32 + swz];
        #pragma unroll
        for (int nf=0; nf<4; ++nf)
            #pragma unroll
            for (int kf=0; kf<2; ++kf)
                b[nf][kf] = *(const s16x8*)&sB[(wn*64+nf*16+lr)*64 + kf*32 + swz];
        __builtin_amdgcn_s_setprio(1);
        #pragma unroll
        for (int kf=0; kf<2; ++kf)
            #pragma unroll
            for (int mf=0; mf<4; ++mf)
                #pragma unroll
                for (int nf=0; nf<4; ++nf)
                    acc[mf][nf] = __builtin_amdgcn_mfma_f32_16x16x32_bf16(a[mf][kf], b[nf][kf], acc[mf][nf], 0, 0, 0);
        __builtin_amdgcn_s_setprio(0);
        __syncthreads();                       // all reads done before next stage overwrites
    }

    float* wbl = (float*)(smem + 17408);
    float* asl = wbl + 2688;
    for (int i=tid; i<2688; i+=256) wbl[i] = wbpart[i];
    for (int i=tid; i<75;   i+=256) asl[i] = asum[n*75 + i];
    __syncthreads();

    #pragma unroll
    for (int nf=0; nf<4; ++nf){
        int cj = wn*64 + nf*16 + lr;
        int j  = jn0 + cj;
        int t  = j/25, v = j - t*25;
        int tc = (t<3) ? t : ((t>124) ? (t-121) : 3);
        float a0 = asl[v], a1 = asl[25+v], a2 = asl[50+v];
        #pragma unroll
        for (int mf=0; mf<4; ++mf)
            #pragma unroll
            for (int r=0; r<4; ++r){
                int m = wm*64 + mf*16 + lg*4 + r;
                float b2v = wbl[m*21+tc]*a0 + wbl[m*21+7+tc]*a1 + wbl[m*21+14+tc]*a2;
                float val = acc[mf][nf][r]*consts[m] + consts[128+m] + b2v
                          + xin[(size_t)n*409600 + (size_t)m*3200 + j];
                val = (val >= 0.f) ? val : 0.1f*val;
                smem[cj*136 + m] = f2bf(val);
            }
    }
    __syncthreads();

    f32x4 acc2[4][4];
    #pragma unroll
    for (int a2=0;a2<4;a2++)
        #pragma unroll
        for (int b2=0;b2<4;b2++) acc2[a2][b2] = (f32x4){0.f,0.f,0.f,0.f};
    #pragma unroll
    for (int kb2=0; kb2<4; ++kb2){
        s16x8 a2[4], b2[4];
        #pragma unroll
        for (int mf=0; mf<4; ++mf)
            a2[mf] = *(const s16x8*)&ffA[(size_t)(wm*64+mf*16+lr)*128 + kb2*32 + lg*8];
        #pragma unroll
        for (int nf=0; nf<4; ++nf)
            b2[nf] = *(const s16x8*)&smem[(wn*64+nf*16+lr)*136 + kb2*32 + lg*8];
        #pragma unroll
        for (int mf=0; mf<4; ++mf)
            #pragma unroll
            for (int nf=0; nf<4; ++nf)
                acc2[mf][nf] = __builtin_amdgcn_mfma_f32_16x16x32_bf16(a2[mf], b2[nf], acc2[mf][nf], 0, 0, 0);
    }

    #pragma unroll
    for (int mf=0; mf<4; ++mf)
        #pragma unroll
        for (int r=0; r<4; ++r){
            int co = wm*64 + mf*16 + lg*4 + r;
            float sc2 = consts[256+co], bi2 = consts[384+co];
            #pragma unroll
            for (int nf=0; nf<4; ++nf){
                int cj = wn*64 + nf*16 + lr;
                size_t idx = (size_t)n*409600 + (size_t)co*3200 + jn0 + cj;
                float val = acc2[mf][nf][r]*sc2 + bi2 + xin[idx];
                val = (val >= 0.f) ? val : 0.1f*val;
                outf[idx] = val;
            }
        }
}

extern "C" void kernel_launch(void* const* d_in, const int* in_sizes, int n_in,
                              void* d_out, int out_size, void* d_ws, size_t ws_size,
                              hipStream_t stream) {
    const float* x      = (const float*)d_in[0];
    const float* theta  = (const float*)d_in[1];
    const float* atts   = (const float*)d_in[2];
    const float* alphas = (const float*)d_in[3];
    const float* v_w    = (const float*)d_in[4];
    const float* v_b    = (const float*)d_in[5];
    const float* out_w  = (const float*)d_in[6];
    const float* out_b  = (const float*)d_in[7];
    const float* out_g  = (const float*)d_in[8];
    const float* out_be = (const float*)d_in[9];
    const float* out_m  = (const float*)d_in[10];
    const float* out_v  = (const float*)d_in[11];
    const float* ff_w   = (const float*)d_in[12];
    const float* ff_b   = (const float*)d_in[13];
    const float* ff_g   = (const float*)d_in[14];
    const float* ff_be  = (const float*)d_in[15];
    const float* ff_m   = (const float*)d_in[16];
    const float* ff_v   = (const float*)d_in[17];
    float* out = (float*)d_out;

    char* w = (char*)d_ws;
    size_t off = 0;
    auto alloc = [&](size_t b){ size_t r = off; off += (b + 1023) & ~(size_t)1023; return r; };
    float*          G      = (float*)         (w + alloc(160000));
    float*          SX     = (float*)         (w + alloc(819200));      // 64*3200 f32
    float*          asumb  = (float*)         (w + alloc(19200));
    float*          consts = (float*)         (w + alloc(2048));
    float*          wbpart = (float*)         (w + alloc(10752));
    float*          pebg   = (float*)         (w + alloc(12800));
    float*          TPgb   = (float*)         (w + alloc(2500));
    unsigned short* att_pad= (unsigned short*)(w + alloc(327680));
    unsigned short* Wr     = (unsigned short*)(w + alloc(688128));
    unsigned short* ffA    = (unsigned short*)(w + alloc(32768));
    unsigned short* xbt    = (unsigned short*)(w + alloc(52428800 + 16384));
    unsigned short* xbu    = (unsigned short*)(w + alloc(67108864));
    unsigned short* ypad   = (unsigned short*)(w + alloc(164659200));

    setup_kernel<<<9344,256,0,stream>>>(x, out_w, ff_w, v_w, v_b, out_b, out_g, out_be, out_m, out_v,
                                        ff_b, ff_g, ff_be, ff_m, ff_v,
                                        consts, ffA, ypad, wbpart, pebg, TPgb, Wr, xbt, xbu, G, SX);
    gram_part<<<512,256,0,stream>>>(xbt, G, SX);
    gram_fin<<<64,256,0,stream>>>(SX, pebg, TPgb, G);
    attn_kernel<<<1,1024,0,stream>>>(G, theta, atts, alphas, att_pad, asumb);
    agg_mfma<<<1024,256,0,stream>>>(att_pad, xbu, ypad);
    gemm_fused<<<1600,256,0,stream>>>(Wr, ypad, x, consts, ffA, wbpart, asumb, out);
}